// Round 8
// baseline (347.908 us; speedup 1.0000x reference)
//
#include <hip/hip_runtime.h>
#include <hip/hip_bf16.h>
#include <math.h>

#define D_MODEL 1024
#define NH      16
#define DK      64
#define S_LEN   2048
#define BATCH   2
#define M_ROWS  4096

typedef _Float16 f16;
typedef _Float16 f16x8 __attribute__((ext_vector_type(8)));
typedef float    f32x4 __attribute__((ext_vector_type(4)));

// native 2^x (v_exp_f32)
__device__ __forceinline__ float exp2_fast(float x) {
    float r;
    asm("v_exp_f32 %0, %1" : "=v"(r) : "v"(x));
    return r;
}

// V key permutation within a 64-block: key' = [b5][b3 b2][b4][b1 b0]
// so PV A-fragment key order pi(g,j) matches contiguous V reads.
__device__ __forceinline__ int perm6(int k) {
    return (k & 35) | ((k & 12) << 1) | ((k & 16) >> 2);
}

// ---------------------------------------------------------------------------
// fp32 -> fp16 conversion: 7 tensors in one launch (y = tensor index).
// y 0..2: Q,K,V (n8big); y 3..6: Wq,Wk,Wv,Wo (n8small).
// ---------------------------------------------------------------------------
__global__ __launch_bounds__(256) void cvt7(
    const float* __restrict__ s0, const float* __restrict__ s1, const float* __restrict__ s2,
    const float* __restrict__ s3, const float* __restrict__ s4, const float* __restrict__ s5,
    const float* __restrict__ s6,
    f16* __restrict__ d0, f16* __restrict__ d1, f16* __restrict__ d2,
    f16* __restrict__ d3, f16* __restrict__ d4, f16* __restrict__ d5,
    f16* __restrict__ d6, int n8big, int n8small) {
    const int y = blockIdx.y;
    const float* s = (y == 0) ? s0 : (y == 1) ? s1 : (y == 2) ? s2 : (y == 3) ? s3
                   : (y == 4) ? s4 : (y == 5) ? s5 : s6;
    f16* d        = (y == 0) ? d0 : (y == 1) ? d1 : (y == 2) ? d2 : (y == 3) ? d3
                   : (y == 4) ? d4 : (y == 5) ? d5 : d6;
    const int n8 = (y < 3) ? n8big : n8small;
    const int i = blockIdx.x * 256 + threadIdx.x;
    if (i >= n8) return;
    const size_t e = (size_t)i * 8;
    const float4 v0 = *(const float4*)&s[e];
    const float4 v1 = *(const float4*)&s[e + 4];
    f16x8 r = {(f16)v0.x, (f16)v0.y, (f16)v0.z, (f16)v0.w,
               (f16)v1.x, (f16)v1.y, (f16)v1.z, (f16)v1.w};
    *(f16x8*)&d[e] = r;
}

// ---------------------------------------------------------------------------
// async global->LDS staging, 16B per lane (HW: wave-uniform base + lane*16)
// ---------------------------------------------------------------------------
__device__ __forceinline__ void stage16(const f16* g, f16* l) {
    __builtin_amdgcn_global_load_lds(
        (const __attribute__((address_space(1))) unsigned int*)g,
        (__attribute__((address_space(3))) unsigned int*)l, 16, 0, 0);
}

// ---------------------------------------------------------------------------
// 128x128 fp16 MFMA GEMM body (normal orientation).
// mode 0: f16 out head-split [b][h][s][dk]; mode 2: f32 out [m][n].
// ---------------------------------------------------------------------------
__device__ __forceinline__ void gemm_body(f16* As, f16* Bs,
                                          const f16* __restrict__ X, const f16* __restrict__ W,
                                          const float* __restrict__ bias, void* __restrict__ Yv,
                                          const int mode, const float oscale) {
    const int tid = threadIdx.x;
    const int lane = tid & 63;
    const int w  = tid >> 6;
    const int wm = w >> 1, wn = w & 1;
    const int l15 = lane & 15, lhi = lane >> 4;
    const int m0 = blockIdx.y * 128, n0 = blockIdx.x * 128;

    const int srow = tid >> 2;
    const int scol = (tid & 3) * 8;

    f32x4 acc[4][4] = {};

    for (int k0 = 0; k0 < D_MODEL; k0 += 32) {
        __syncthreads();
        stage16(&X[(size_t)(m0 + srow) * D_MODEL + k0 + scol],      &As[tid * 8]);
        stage16(&X[(size_t)(m0 + 64 + srow) * D_MODEL + k0 + scol], &As[2048 + tid * 8]);
        stage16(&W[(size_t)(n0 + srow) * D_MODEL + k0 + scol],      &Bs[tid * 8]);
        stage16(&W[(size_t)(n0 + 64 + srow) * D_MODEL + k0 + scol], &Bs[2048 + tid * 8]);
        __syncthreads();
        f16x8 af[4], bf[4];
#pragma unroll
        for (int mt = 0; mt < 4; ++mt) af[mt] = *(const f16x8*)&As[(wm * 64 + mt * 16 + l15) * 32 + lhi * 8];
#pragma unroll
        for (int nt = 0; nt < 4; ++nt) bf[nt] = *(const f16x8*)&Bs[(wn * 64 + nt * 16 + l15) * 32 + lhi * 8];
#pragma unroll
        for (int mt = 0; mt < 4; ++mt)
#pragma unroll
            for (int nt = 0; nt < 4; ++nt)
                acc[mt][nt] = __builtin_amdgcn_mfma_f32_16x16x32_f16(af[mt], bf[nt], acc[mt][nt], 0, 0, 0);
    }

#pragma unroll
    for (int mt = 0; mt < 4; ++mt)
#pragma unroll
        for (int nt = 0; nt < 4; ++nt) {
            const int n = n0 + wn * 64 + nt * 16 + l15;
            const float bn = bias[n];
#pragma unroll
            for (int r = 0; r < 4; ++r) {
                const int m = m0 + wm * 64 + mt * 16 + lhi * 4 + r;
                const float v = (acc[mt][nt][r] + bn) * oscale;
                if (mode == 0) {
                    ((f16*)Yv)[((((size_t)(m >> 11) * NH + (n >> 6)) * S_LEN) + (m & 2047)) * DK + (n & 63)] = (f16)v;
                } else {
                    ((float*)Yv)[(size_t)m * D_MODEL + n] = v;
                }
            }
        }
}

// ---------------------------------------------------------------------------
// 128x128 OPERAND-SWAPPED body for the V projection: A=W rows (n), B=X rows
// (m) -> D[row=n][col=m]. Lanes run along m=s -> coalesced-ish writes into
// the transposed, key-permuted layout vt[bh][dk][s'] (s' = perm6 in 64-blk).
// ---------------------------------------------------------------------------
__device__ __forceinline__ void gemm_body_vswap(f16* As, f16* Bs,
                                                const f16* __restrict__ X, const f16* __restrict__ W,
                                                const float* __restrict__ bias, f16* __restrict__ vt) {
    const int tid = threadIdx.x;
    const int lane = tid & 63;
    const int w  = tid >> 6;
    const int wm = w >> 1, wn = w & 1;
    const int l15 = lane & 15, lhi = lane >> 4;
    const int m0 = blockIdx.y * 128, n0 = blockIdx.x * 128;

    const int srow = tid >> 2;
    const int scol = (tid & 3) * 8;

    f32x4 acc[4][4] = {};

    for (int k0 = 0; k0 < D_MODEL; k0 += 32) {
        __syncthreads();
        stage16(&X[(size_t)(m0 + srow) * D_MODEL + k0 + scol],      &As[tid * 8]);
        stage16(&X[(size_t)(m0 + 64 + srow) * D_MODEL + k0 + scol], &As[2048 + tid * 8]);
        stage16(&W[(size_t)(n0 + srow) * D_MODEL + k0 + scol],      &Bs[tid * 8]);
        stage16(&W[(size_t)(n0 + 64 + srow) * D_MODEL + k0 + scol], &Bs[2048 + tid * 8]);
        __syncthreads();
        f16x8 af[4], bf[4];
#pragma unroll
        for (int at = 0; at < 4; ++at) af[at] = *(const f16x8*)&Bs[(wm * 64 + at * 16 + l15) * 32 + lhi * 8];
#pragma unroll
        for (int bt = 0; bt < 4; ++bt) bf[bt] = *(const f16x8*)&As[(wn * 64 + bt * 16 + l15) * 32 + lhi * 8];
#pragma unroll
        for (int at = 0; at < 4; ++at)
#pragma unroll
            for (int bt = 0; bt < 4; ++bt)
                acc[at][bt] = __builtin_amdgcn_mfma_f32_16x16x32_f16(af[at], bf[bt], acc[at][bt], 0, 0, 0);
    }

#pragma unroll
    for (int at = 0; at < 4; ++at)
#pragma unroll
        for (int bt = 0; bt < 4; ++bt) {
            const int m = m0 + wn * 64 + bt * 16 + l15;   // = b*2048 + s
            const int b = m >> 11, s = m & 2047;
#pragma unroll
            for (int r = 0; r < 4; ++r) {
                const int n = n0 + wm * 64 + at * 16 + lhi * 4 + r;  // = h*64 + d
                const float v = acc[at][bt][r] + bias[n];
                const int s2 = (s & ~63) | perm6(s & 63);
                vt[(((size_t)b * NH + (n >> 6)) * DK + (n & 63)) * S_LEN + s2] = (f16)v;
            }
        }
}

__global__ __launch_bounds__(256) void qkv_gemm(
    const f16* __restrict__ Xq, const f16* __restrict__ Xk, const f16* __restrict__ Xv,
    const f16* __restrict__ Wq, const f16* __restrict__ Wk, const f16* __restrict__ Wv,
    const float* __restrict__ bq, const float* __restrict__ bk, const float* __restrict__ bv,
    f16* __restrict__ qh, f16* __restrict__ kh, f16* __restrict__ vt) {
    __shared__ f16 As[128 * 32];
    __shared__ f16 Bs[128 * 32];
    const int z = blockIdx.z;
    if (z == 2) {
        gemm_body_vswap(As, Bs, Xv, Wv, bv, vt);
    } else if (z == 0) {
        // fold softmax scale 1/sqrt(64) AND log2(e) into Q projection
        gemm_body(As, Bs, Xq, Wq, bq, qh, 0, 0.125f * 1.44269504f);
    } else {
        gemm_body(As, Bs, Xk, Wk, bk, kh, 0, 1.0f);
    }
}

// ---------------------------------------------------------------------------
// Output GEMM, 64x128 tiles (grid 8x64 = 512 blocks = 2/CU), f32 out.
// ---------------------------------------------------------------------------
__global__ __launch_bounds__(256) void out_gemm(const f16* __restrict__ X, const f16* __restrict__ W,
                                                const float* __restrict__ bias, float* __restrict__ Y) {
    __shared__ f16 As[64 * 32];
    __shared__ f16 Bs[128 * 32];
    const int tid = threadIdx.x;
    const int lane = tid & 63;
    const int w  = tid >> 6;
    const int l15 = lane & 15, lhi = lane >> 4;
    const int m0 = blockIdx.y * 64, n0 = blockIdx.x * 128;

    const int srow = tid >> 2;
    const int scol = (tid & 3) * 8;

    f32x4 acc[4][2] = {};

    for (int k0 = 0; k0 < D_MODEL; k0 += 32) {
        __syncthreads();
        stage16(&X[(size_t)(m0 + srow) * D_MODEL + k0 + scol],      &As[tid * 8]);
        stage16(&W[(size_t)(n0 + srow) * D_MODEL + k0 + scol],      &Bs[tid * 8]);
        stage16(&W[(size_t)(n0 + 64 + srow) * D_MODEL + k0 + scol], &Bs[2048 + tid * 8]);
        __syncthreads();
        f16x8 af[4], bf[2];
#pragma unroll
        for (int mt = 0; mt < 4; ++mt) af[mt] = *(const f16x8*)&As[(mt * 16 + l15) * 32 + lhi * 8];
#pragma unroll
        for (int nt = 0; nt < 2; ++nt) bf[nt] = *(const f16x8*)&Bs[(w * 32 + nt * 16 + l15) * 32 + lhi * 8];
#pragma unroll
        for (int mt = 0; mt < 4; ++mt)
#pragma unroll
            for (int nt = 0; nt < 2; ++nt)
                acc[mt][nt] = __builtin_amdgcn_mfma_f32_16x16x32_f16(af[mt], bf[nt], acc[mt][nt], 0, 0, 0);
    }

#pragma unroll
    for (int mt = 0; mt < 4; ++mt)
#pragma unroll
        for (int nt = 0; nt < 2; ++nt) {
            const int n = n0 + w * 32 + nt * 16 + l15;
            const float bn = bias[n];
#pragma unroll
            for (int r = 0; r < 4; ++r) {
                const int m = m0 + mt * 16 + lhi * 4 + r;
                Y[(size_t)m * D_MODEL + n] = acc[mt][nt][r] + bn;
            }
        }
}

// ---------------------------------------------------------------------------
// MFMA flash attention (R6 structure, 2 K-tiles per barrier pair).
// Grid (qt=S/64, bh=32). 4 waves x 16 q-rows. Swapped QK^T, exp2 softmax,
// defer-max, reg-prefetch of the next 128-key block, perm6-keyed V.
// LDS: Ks[2]/Vs[2] 64x72 f16 tiles = 36 KB -> 4 blocks/CU.
// ---------------------------------------------------------------------------
__global__ __launch_bounds__(256) void flash_mfma(const f16* __restrict__ qh, const f16* __restrict__ kh,
                                                  const f16* __restrict__ vt, f16* __restrict__ ao) {
    __shared__ f16 Ks[2][64][72];    // [sub][key][dk]
    __shared__ f16 Vs[2][64][72];    // [sub][dk][key'] (perm6 key order)

    const int tid = threadIdx.x;
    const int lane = tid & 63;
    const int w = tid >> 6;
    const int c = lane & 15;      // q column (softmax owner) / d column (PV)
    const int g = lane >> 4;
    const int qt = blockIdx.x, bh = blockIdx.y;
    const int b = bh >> 4, h = bh & 15;
    const int qrow0 = qt * 64 + w * 16;

    // Q as B-operand (pre-scaled by 0.125*log2e in the projection)
    f16x8 bQ0, bQ1;
    {
        const f16* qp = qh + ((size_t)bh * S_LEN + qrow0 + c) * DK;
        bQ0 = *(const f16x8*)&qp[g * 8];
        bQ1 = *(const f16x8*)&qp[32 + g * 8];
    }

    f32x4 oa[4] = {};                 // O[q=g*4+r][d=nt2*16+c]
    float m_run = -INFINITY;          // log2-space running max for q=c
    float l_run = 0.f;

    const int cr = tid >> 3;          // staging row 0..31 (+32)
    const int cs = (tid & 7) * 8;

    const f16* kbase = kh + (size_t)bh * S_LEN * DK;
    const f16* vbase = vt + (size_t)bh * DK * S_LEN;

    // prologue: reg-stage 128-key block 0
    uint4 kr[2][2], vr[2][2];
#pragma unroll
    for (int s = 0; s < 2; ++s) {
        kr[s][0] = *(const uint4*)&kbase[(size_t)(s * 64 + cr) * DK + cs];
        kr[s][1] = *(const uint4*)&kbase[(size_t)(s * 64 + cr + 32) * DK + cs];
        vr[s][0] = *(const uint4*)&vbase[(size_t)cr * S_LEN + s * 64 + cs];
        vr[s][1] = *(const uint4*)&vbase[(size_t)(cr + 32) * S_LEN + s * 64 + cs];
    }

    for (int bt = 0; bt < S_LEN / 128; ++bt) {
        __syncthreads();              // previous block's LDS reads done
#pragma unroll
        for (int s = 0; s < 2; ++s) {
            *(uint4*)&Ks[s][cr][cs]      = kr[s][0];
            *(uint4*)&Ks[s][cr + 32][cs] = kr[s][1];
            *(uint4*)&Vs[s][cr][cs]      = vr[s][0];
            *(uint4*)&Vs[s][cr + 32][cs] = vr[s][1];
        }
        if (bt + 1 < S_LEN / 128) {   // prefetch next 128-key block into regs
            const int o = (bt + 1) * 128;
#pragma unroll
            for (int s = 0; s < 2; ++s) {
                kr[s][0] = *(const uint4*)&kbase[(size_t)(o + s * 64 + cr) * DK + cs];
                kr[s][1] = *(const uint4*)&kbase[(size_t)(o + s * 64 + cr + 32) * DK + cs];
                vr[s][0] = *(const uint4*)&vbase[(size_t)cr * S_LEN + o + s * 64 + cs];
                vr[s][1] = *(const uint4*)&vbase[(size_t)(cr + 32) * S_LEN + o + s * 64 + cs];
            }
        }
        __syncthreads();

#pragma unroll
        for (int sub = 0; sub < 2; ++sub) {
            // swapped QK^T: sc[nt][r] = S'[key=nt*16+g*4+r][q=c] (log2 units)
            f32x4 sc[4] = {};
            __builtin_amdgcn_s_setprio(1);
#pragma unroll
            for (int nt = 0; nt < 4; ++nt) {
                const f16x8 ka = *(const f16x8*)&Ks[sub][nt * 16 + c][g * 8];
                const f16x8 kb = *(const f16x8*)&Ks[sub][nt * 16 + c][32 + g * 8];
                sc[nt] = __builtin_amdgcn_mfma_f32_16x16x32_f16(ka, bQ0, sc[nt], 0, 0, 0);
                sc[nt] = __builtin_amdgcn_mfma_f32_16x16x32_f16(kb, bQ1, sc[nt], 0, 0, 0);
            }
            __builtin_amdgcn_s_setprio(0);

            // softmax for q=c: lane-local 16 keys + 2 cross-group shfls
            float tmax = sc[0][0];
#pragma unroll
            for (int nt = 0; nt < 4; ++nt)
#pragma unroll
                for (int r = 0; r < 4; ++r) tmax = fmaxf(tmax, sc[nt][r]);
            tmax = fmaxf(tmax, __shfl_xor(tmax, 16));
            tmax = fmaxf(tmax, __shfl_xor(tmax, 32));

            // defer-max (T13): rescale only when some row's max grew by >8
            if (!__all(tmax <= m_run + 8.f)) {
                const float mnew = fmaxf(m_run, tmax);
                const float fac = exp2_fast(m_run - mnew);   // 0 on first tile
                m_run = mnew;
                l_run *= fac;
#pragma unroll
                for (int r = 0; r < 4; ++r) {
                    const float fr = __shfl(fac, (lane & 48) + ((lane >> 4) & 3) * 4 + r);
                    oa[0][r] *= fr; oa[1][r] *= fr; oa[2][r] *= fr; oa[3][r] *= fr;
                }
            }

            float e[4][4];
            float tsum = 0.f;
#pragma unroll
            for (int nt = 0; nt < 4; ++nt)
#pragma unroll
                for (int r = 0; r < 4; ++r) {
                    e[nt][r] = exp2_fast(sc[nt][r] - m_run);
                    tsum += e[nt][r];
                }
            tsum += __shfl_xor(tsum, 16);
            tsum += __shfl_xor(tsum, 32);
            l_run += tsum;

            // PV: A-fragment = lane's own exp values (key order = perm6 inverse)
            const f16x8 aP0 = {(f16)e[0][0], (f16)e[0][1], (f16)e[0][2], (f16)e[0][3],
                               (f16)e[1][0], (f16)e[1][1], (f16)e[1][2], (f16)e[1][3]};
            const f16x8 aP1 = {(f16)e[2][0], (f16)e[2][1], (f16)e[2][2], (f16)e[2][3],
                               (f16)e[3][0], (f16)e[3][1], (f16)e[3][2], (f16)e[3][3]};

            __builtin_amdgcn_s_setprio(1);
#pragma unroll
            for (int nt2 = 0; nt2 < 4; ++nt2) {
                const f16x8 b0 = *(const f16x8*)&Vs[sub][nt2 * 16 + c][g * 8];        // keys' 0..31
                const f16x8 b1 = *(const f16x8*)&Vs[sub][nt2 * 16 + c][32 + g * 8];   // keys' 32..63
                oa[nt2] = __builtin_amdgcn_mfma_f32_16x16x32_f16(aP0, b0, oa[nt2], 0, 0, 0);
                oa[nt2] = __builtin_amdgcn_mfma_f32_16x16x32_f16(aP1, b1, oa[nt2], 0, 0, 0);
            }
            __builtin_amdgcn_s_setprio(0);
        }
    }

    // epilogue
    const float invc = 1.f / l_run;
#pragma unroll
    for (int r = 0; r < 4; ++r) {
        const float ir = __shfl(invc, (lane & 48) + ((lane >> 4) & 3) * 4 + r);
        const int srow = qrow0 + ((lane >> 4) & 3) * 4 + r;
#pragma unroll
        for (int nt2 = 0; nt2 < 4; ++nt2) {
            ao[((size_t)b * S_LEN + srow) * D_MODEL + h * DK + nt2 * 16 + c] = (f16)(oa[nt2][r] * ir);
        }
    }
}

// ---------------------------------------------------------------------------
extern "C" void kernel_launch(void* const* d_in, const int* in_sizes, int n_in,
                              void* d_out, int out_size, void* d_ws, size_t ws_size,
                              hipStream_t stream) {
    const float* Q  = (const float*)d_in[0];
    const float* K  = (const float*)d_in[1];
    const float* V  = (const float*)d_in[2];
    const float* Wq = (const float*)d_in[3];
    const float* bq = (const float*)d_in[4];
    const float* Wk = (const float*)d_in[5];
    const float* bk = (const float*)d_in[6];
    const float* Wv = (const float*)d_in[7];
    const float* bv = (const float*)d_in[8];
    const float* Wo = (const float*)d_in[9];
    const float* bo = (const float*)d_in[10];
    float* out = (float*)d_out;

    const size_t NELEM = (size_t)M_ROWS * D_MODEL;   // 4M
    const size_t WELEM = (size_t)D_MODEL * D_MODEL;  // 1M
    f16* Qf  = (f16*)d_ws;
    f16* Kf  = Qf + NELEM;
    f16* Vf  = Kf + NELEM;
    f16* Wqf = Vf + NELEM;
    f16* Wkf = Wqf + WELEM;
    f16* Wvf = Wkf + WELEM;
    f16* Wof = Wvf + WELEM;
    f16* qh  = Wof + WELEM;   // [bh][s][dk], pre-scaled by 0.125*log2e
    f16* kh  = qh + NELEM;    // [bh][s][dk]
    f16* vtw = kh + NELEM;    // [bh][dk][s'] (perm6 key order)
    f16* aow = vtw + NELEM;   // [b][s][d_model] f16

    cvt7<<<dim3(2048, 7), 256, 0, stream>>>(Q, K, V, Wq, Wk, Wv, Wo,
                                            Qf, Kf, Vf, Wqf, Wkf, Wvf, Wof,
                                            (int)(NELEM / 8), (int)(WELEM / 8));
    qkv_gemm<<<dim3(D_MODEL / 128, M_ROWS / 128, 3), 256, 0, stream>>>(
        Qf, Kf, Vf, Wqf, Wkf, Wvf, bq, bk, bv, qh, kh, vtw);
    flash_mfma<<<dim3(S_LEN / 64, BATCH * NH), 256, 0, stream>>>(qh, kh, vtw, aow);
    out_gemm<<<dim3(D_MODEL / 128, M_ROWS / 64), 256, 0, stream>>>(aow, Wof, bo, out);
}

// Round 9
// 253.992 us; speedup vs baseline: 1.3698x; 1.3698x over previous
//
#include <hip/hip_runtime.h>
#include <hip/hip_bf16.h>
#include <math.h>

#define D_MODEL 1024
#define NH      16
#define DK      64
#define S_LEN   2048
#define BATCH   2
#define M_ROWS  4096

typedef _Float16 f16;
typedef _Float16 f16x8 __attribute__((ext_vector_type(8)));
typedef float    f32x4 __attribute__((ext_vector_type(4)));

// native 2^x (v_exp_f32)
__device__ __forceinline__ float exp2_fast(float x) {
    float r;
    asm("v_exp_f32 %0, %1" : "=v"(r) : "v"(x));
    return r;
}

// V key permutation within a 64-block: key' = [b5][b3 b2][b4][b1 b0]
// so PV A-fragment key order pi(g,j) matches contiguous V reads.
__device__ __forceinline__ int perm6(int k) {
    return (k & 35) | ((k & 12) << 1) | ((k & 16) >> 2);
}

// ---------------------------------------------------------------------------
// fp32 -> fp16 conversion: 7 tensors in one launch (y = tensor index).
// ---------------------------------------------------------------------------
__global__ __launch_bounds__(256) void cvt7(
    const float* __restrict__ s0, const float* __restrict__ s1, const float* __restrict__ s2,
    const float* __restrict__ s3, const float* __restrict__ s4, const float* __restrict__ s5,
    const float* __restrict__ s6,
    f16* __restrict__ d0, f16* __restrict__ d1, f16* __restrict__ d2,
    f16* __restrict__ d3, f16* __restrict__ d4, f16* __restrict__ d5,
    f16* __restrict__ d6, int n8big, int n8small) {
    const int y = blockIdx.y;
    const float* s = (y == 0) ? s0 : (y == 1) ? s1 : (y == 2) ? s2 : (y == 3) ? s3
                   : (y == 4) ? s4 : (y == 5) ? s5 : s6;
    f16* d        = (y == 0) ? d0 : (y == 1) ? d1 : (y == 2) ? d2 : (y == 3) ? d3
                   : (y == 4) ? d4 : (y == 5) ? d5 : d6;
    const int n8 = (y < 3) ? n8big : n8small;
    const int i = blockIdx.x * 256 + threadIdx.x;
    if (i >= n8) return;
    const size_t e = (size_t)i * 8;
    const float4 v0 = *(const float4*)&s[e];
    const float4 v1 = *(const float4*)&s[e + 4];
    f16x8 r = {(f16)v0.x, (f16)v0.y, (f16)v0.z, (f16)v0.w,
               (f16)v1.x, (f16)v1.y, (f16)v1.z, (f16)v1.w};
    *(f16x8*)&d[e] = r;
}

// ---------------------------------------------------------------------------
// async global->LDS staging, 16B per lane (HW: wave-uniform base + lane*16)
// ---------------------------------------------------------------------------
__device__ __forceinline__ void stage16(const f16* g, f16* l) {
    __builtin_amdgcn_global_load_lds(
        (const __attribute__((address_space(1))) unsigned int*)g,
        (__attribute__((address_space(3))) unsigned int*)l, 16, 0, 0);
}

// ---------------------------------------------------------------------------
// 128x128 fp16 MFMA GEMM body (normal orientation), LDS-bounce epilogue.
// mode 0: f16 out head-split [b][h][s][dk] via 16B vector stores.
// mode 2: f32 out [m][n] direct.
// ---------------------------------------------------------------------------
__device__ __forceinline__ void gemm_body(f16* As, f16* Bs,
                                          const f16* __restrict__ X, const f16* __restrict__ W,
                                          const float* __restrict__ bias, void* __restrict__ Yv,
                                          const int mode, const float oscale) {
    const int tid = threadIdx.x;
    const int lane = tid & 63;
    const int w  = tid >> 6;
    const int wm = w >> 1, wn = w & 1;
    const int l15 = lane & 15, lhi = lane >> 4;
    const int m0 = blockIdx.y * 128, n0 = blockIdx.x * 128;

    const int srow = tid >> 2;
    const int scol = (tid & 3) * 8;

    f32x4 acc[4][4] = {};

    for (int k0 = 0; k0 < D_MODEL; k0 += 32) {
        __syncthreads();
        stage16(&X[(size_t)(m0 + srow) * D_MODEL + k0 + scol],      &As[tid * 8]);
        stage16(&X[(size_t)(m0 + 64 + srow) * D_MODEL + k0 + scol], &As[2048 + tid * 8]);
        stage16(&W[(size_t)(n0 + srow) * D_MODEL + k0 + scol],      &Bs[tid * 8]);
        stage16(&W[(size_t)(n0 + 64 + srow) * D_MODEL + k0 + scol], &Bs[2048 + tid * 8]);
        __syncthreads();
        f16x8 af[4], bf[4];
#pragma unroll
        for (int mt = 0; mt < 4; ++mt) af[mt] = *(const f16x8*)&As[(wm * 64 + mt * 16 + l15) * 32 + lhi * 8];
#pragma unroll
        for (int nt = 0; nt < 4; ++nt) bf[nt] = *(const f16x8*)&Bs[(wn * 64 + nt * 16 + l15) * 32 + lhi * 8];
#pragma unroll
        for (int mt = 0; mt < 4; ++mt)
#pragma unroll
            for (int nt = 0; nt < 4; ++nt)
                acc[mt][nt] = __builtin_amdgcn_mfma_f32_16x16x32_f16(af[mt], bf[nt], acc[mt][nt], 0, 0, 0);
    }

    if (mode == 2) {
#pragma unroll
        for (int mt = 0; mt < 4; ++mt)
#pragma unroll
            for (int nt = 0; nt < 4; ++nt) {
                const int n = n0 + wn * 64 + nt * 16 + l15;
                const float bn = bias[n];
#pragma unroll
                for (int r = 0; r < 4; ++r) {
                    const int m = m0 + wm * 64 + mt * 16 + lhi * 4 + r;
                    ((float*)Yv)[(size_t)m * D_MODEL + n] = (acc[mt][nt][r] + bn) * oscale;
                }
            }
        return;
    }

    // mode 0: LDS-bounce epilogue. Wave tile = 64x64 f16 = 8KB; As/Bs hold 2
    // waves per phase. n-base (n0+wn*64) is 64-aligned -> single head per wave.
    f16* pool = (w & 1) ? Bs : As;
    const int myphase = w >> 1;
#pragma unroll
    for (int phase = 0; phase < 2; ++phase) {
        __syncthreads();
        if (myphase == phase) {
#pragma unroll
            for (int nt = 0; nt < 4; ++nt) {
                const int n = n0 + wn * 64 + nt * 16 + l15;
                const float bn = bias[n];
#pragma unroll
                for (int mt = 0; mt < 4; ++mt)
#pragma unroll
                    for (int r = 0; r < 4; ++r)
                        pool[(mt * 16 + lhi * 4 + r) * 64 + nt * 16 + l15] =
                            (f16)((acc[mt][nt][r] + bn) * oscale);
        }
        }
        __syncthreads();
        if (myphase == phase) {
            const int nbase = n0 + wn * 64;
            const int h = nbase >> 6;
            const int col = (lane & 7) * 8;
#pragma unroll
            for (int t = 0; t < 8; ++t) {
                const int row = t * 8 + (lane >> 3);
                const int m = m0 + wm * 64 + row;
                const int b = m >> 11, s = m & 2047;
                const f16x8 v = *(const f16x8*)&pool[row * 64 + col];
                *(f16x8*)&((f16*)Yv)[((((size_t)b * NH + h) * S_LEN) + s) * DK + col] = v;
            }
        }
    }
}

// ---------------------------------------------------------------------------
// 128x128 OPERAND-SWAPPED V-projection body: A=W rows (n), B=X rows (m) ->
// D[row=n][col=m=s]. LDS-bounce epilogue applies perm6 inside LDS, then
// 16B-contiguous stores into vt[bh][dk][s'].
// ---------------------------------------------------------------------------
__device__ __forceinline__ void gemm_body_vswap(f16* As, f16* Bs,
                                                const f16* __restrict__ X, const f16* __restrict__ W,
                                                const float* __restrict__ bias, f16* __restrict__ vt) {
    const int tid = threadIdx.x;
    const int lane = tid & 63;
    const int w  = tid >> 6;
    const int wm = w >> 1, wn = w & 1;
    const int l15 = lane & 15, lhi = lane >> 4;
    const int m0 = blockIdx.y * 128, n0 = blockIdx.x * 128;

    const int srow = tid >> 2;
    const int scol = (tid & 3) * 8;

    f32x4 acc[4][4] = {};

    for (int k0 = 0; k0 < D_MODEL; k0 += 32) {
        __syncthreads();
        stage16(&X[(size_t)(m0 + srow) * D_MODEL + k0 + scol],      &As[tid * 8]);
        stage16(&X[(size_t)(m0 + 64 + srow) * D_MODEL + k0 + scol], &As[2048 + tid * 8]);
        stage16(&W[(size_t)(n0 + srow) * D_MODEL + k0 + scol],      &Bs[tid * 8]);
        stage16(&W[(size_t)(n0 + 64 + srow) * D_MODEL + k0 + scol], &Bs[2048 + tid * 8]);
        __syncthreads();
        f16x8 af[4], bf[4];
#pragma unroll
        for (int at = 0; at < 4; ++at) af[at] = *(const f16x8*)&Bs[(wm * 64 + at * 16 + l15) * 32 + lhi * 8];
#pragma unroll
        for (int bt = 0; bt < 4; ++bt) bf[bt] = *(const f16x8*)&As[(wn * 64 + bt * 16 + l15) * 32 + lhi * 8];
#pragma unroll
        for (int at = 0; at < 4; ++at)
#pragma unroll
            for (int bt = 0; bt < 4; ++bt)
                acc[at][bt] = __builtin_amdgcn_mfma_f32_16x16x32_f16(af[at], bf[bt], acc[at][bt], 0, 0, 0);
    }

    // LDS-bounce: wave tile 64(d) x 64(s) f16, perm6 applied on the LDS write.
    f16* pool = (w & 1) ? Bs : As;
    const int myphase = w >> 1;
#pragma unroll
    for (int phase = 0; phase < 2; ++phase) {
        __syncthreads();
        if (myphase == phase) {
#pragma unroll
            for (int at = 0; at < 4; ++at)
#pragma unroll
                for (int r = 0; r < 4; ++r) {
                    const int nl = at * 16 + lhi * 4 + r;               // d within wave
                    const float bn = bias[n0 + wm * 64 + nl];
#pragma unroll
                    for (int bt = 0; bt < 4; ++bt)
                        pool[nl * 64 + perm6(bt * 16 + l15)] = (f16)(acc[at][bt][r] + bn);
                }
        }
        __syncthreads();
        if (myphase == phase) {
            const int nbase = n0 + wm * 64;                 // 64-aligned: one head
            const int h = nbase >> 6;
            const int mbase = m0 + wn * 64;                 // 64-aligned s block
            const int b = mbase >> 11, sblk = mbase & 2047;
            const int col = (lane & 7) * 8;
#pragma unroll
            for (int t = 0; t < 8; ++t) {
                const int row = t * 8 + (lane >> 3);        // d
                const f16x8 v = *(const f16x8*)&pool[row * 64 + col];
                *(f16x8*)&vt[(((size_t)b * NH + h) * DK + row) * S_LEN + sblk + col] = v;
            }
        }
    }
}

__global__ __launch_bounds__(256) void qkv_gemm(
    const f16* __restrict__ Xq, const f16* __restrict__ Xk, const f16* __restrict__ Xv,
    const f16* __restrict__ Wq, const f16* __restrict__ Wk, const f16* __restrict__ Wv,
    const float* __restrict__ bq, const float* __restrict__ bk, const float* __restrict__ bv,
    f16* __restrict__ qh, f16* __restrict__ kh, f16* __restrict__ vt) {
    __shared__ f16 As[128 * 32];
    __shared__ f16 Bs[128 * 32];
    const int z = blockIdx.z;
    if (z == 2) {
        gemm_body_vswap(As, Bs, Xv, Wv, bv, vt);
    } else if (z == 0) {
        // fold softmax scale 1/sqrt(64) AND log2(e) into Q projection
        gemm_body(As, Bs, Xq, Wq, bq, qh, 0, 0.125f * 1.44269504f);
    } else {
        gemm_body(As, Bs, Xk, Wk, bk, kh, 0, 1.0f);
    }
}

// ---------------------------------------------------------------------------
// Output GEMM, 64x128 tiles (grid 8x64 = 512 blocks = 2/CU), f32 out.
// ---------------------------------------------------------------------------
__global__ __launch_bounds__(256) void out_gemm(const f16* __restrict__ X, const f16* __restrict__ W,
                                                const float* __restrict__ bias, float* __restrict__ Y) {
    __shared__ f16 As[64 * 32];
    __shared__ f16 Bs[128 * 32];
    const int tid = threadIdx.x;
    const int lane = tid & 63;
    const int w  = tid >> 6;
    const int l15 = lane & 15, lhi = lane >> 4;
    const int m0 = blockIdx.y * 64, n0 = blockIdx.x * 128;

    const int srow = tid >> 2;
    const int scol = (tid & 3) * 8;

    f32x4 acc[4][2] = {};

    for (int k0 = 0; k0 < D_MODEL; k0 += 32) {
        __syncthreads();
        stage16(&X[(size_t)(m0 + srow) * D_MODEL + k0 + scol],      &As[tid * 8]);
        stage16(&W[(size_t)(n0 + srow) * D_MODEL + k0 + scol],      &Bs[tid * 8]);
        stage16(&W[(size_t)(n0 + 64 + srow) * D_MODEL + k0 + scol], &Bs[2048 + tid * 8]);
        __syncthreads();
        f16x8 af[4], bf[2];
#pragma unroll
        for (int mt = 0; mt < 4; ++mt) af[mt] = *(const f16x8*)&As[(mt * 16 + l15) * 32 + lhi * 8];
#pragma unroll
        for (int nt = 0; nt < 2; ++nt) bf[nt] = *(const f16x8*)&Bs[(w * 32 + nt * 16 + l15) * 32 + lhi * 8];
#pragma unroll
        for (int mt = 0; mt < 4; ++mt)
#pragma unroll
            for (int nt = 0; nt < 2; ++nt)
                acc[mt][nt] = __builtin_amdgcn_mfma_f32_16x16x32_f16(af[mt], bf[nt], acc[mt][nt], 0, 0, 0);
    }

#pragma unroll
    for (int mt = 0; mt < 4; ++mt)
#pragma unroll
        for (int nt = 0; nt < 2; ++nt) {
            const int n = n0 + w * 32 + nt * 16 + l15;
            const float bn = bias[n];
#pragma unroll
            for (int r = 0; r < 4; ++r) {
                const int m = m0 + mt * 16 + lhi * 4 + r;
                Y[(size_t)m * D_MODEL + n] = acc[mt][nt][r] + bn;
            }
        }
}

// ---------------------------------------------------------------------------
// MFMA flash attention (R6 structure — measured 70.5 us). Grid (qt, bh).
// 4 waves x 16 q-rows. Swapped QK^T, exp2 softmax, defer-max, reg-prefetch
// of next 64-key tile (4 uint4 = 16 staging VGPRs, no spill), perm6-keyed V.
// ---------------------------------------------------------------------------
__global__ __launch_bounds__(256) void flash_mfma(const f16* __restrict__ qh, const f16* __restrict__ kh,
                                                  const f16* __restrict__ vt, f16* __restrict__ ao) {
    __shared__ f16 Ks[64][72];    // [key][dk]
    __shared__ f16 Vs[64][72];    // [dk][key'] (perm6 key order)

    const int tid = threadIdx.x;
    const int lane = tid & 63;
    const int w = tid >> 6;
    const int c = lane & 15;      // q column (softmax owner) / d column (PV)
    const int g = lane >> 4;
    const int qt = blockIdx.x, bh = blockIdx.y;
    const int b = bh >> 4, h = bh & 15;
    const int qrow0 = qt * 64 + w * 16;

    // Q as B-operand (pre-scaled by 0.125*log2e in the projection)
    f16x8 bQ0, bQ1;
    {
        const f16* qp = qh + ((size_t)bh * S_LEN + qrow0 + c) * DK;
        bQ0 = *(const f16x8*)&qp[g * 8];
        bQ1 = *(const f16x8*)&qp[32 + g * 8];
    }

    f32x4 oa[4] = {};                 // O[q=g*4+r][d=nt2*16+c]
    float m_run = -INFINITY;          // log2-space running max for q=c
    float l_run = 0.f;

    const int cr = tid >> 3;          // staging row 0..31 (+32)
    const int cs = (tid & 7) * 8;

    const f16* kbase = kh + (size_t)bh * S_LEN * DK;
    const f16* vbase = vt + (size_t)bh * DK * S_LEN;

    // prologue: reg-stage tile 0
    uint4 kA = *(const uint4*)&kbase[(size_t)(cr) * DK + cs];
    uint4 kB = *(const uint4*)&kbase[(size_t)(cr + 32) * DK + cs];
    uint4 vA = *(const uint4*)&vbase[(size_t)cr * S_LEN + cs];
    uint4 vB = *(const uint4*)&vbase[(size_t)(cr + 32) * S_LEN + cs];

    for (int kt = 0; kt < S_LEN / 64; ++kt) {
        __syncthreads();              // previous tile's LDS reads done
        *(uint4*)&Ks[cr][cs]      = kA;
        *(uint4*)&Ks[cr + 32][cs] = kB;
        *(uint4*)&Vs[cr][cs]      = vA;
        *(uint4*)&Vs[cr + 32][cs] = vB;
        if (kt + 1 < S_LEN / 64) {    // async prefetch next tile into regs
            const int o = (kt + 1) * 64;
            kA = *(const uint4*)&kbase[(size_t)(o + cr) * DK + cs];
            kB = *(const uint4*)&kbase[(size_t)(o + cr + 32) * DK + cs];
            vA = *(const uint4*)&vbase[(size_t)cr * S_LEN + o + cs];
            vB = *(const uint4*)&vbase[(size_t)(cr + 32) * S_LEN + o + cs];
        }
        __syncthreads();

        // swapped QK^T: sc[nt][r] = S'[key=nt*16+g*4+r][q=c] (log2 units)
        f32x4 sc[4] = {};
        __builtin_amdgcn_s_setprio(1);
#pragma unroll
        for (int nt = 0; nt < 4; ++nt) {
            const f16x8 ka = *(const f16x8*)&Ks[nt * 16 + c][g * 8];
            const f16x8 kb = *(const f16x8*)&Ks[nt * 16 + c][32 + g * 8];
            sc[nt] = __builtin_amdgcn_mfma_f32_16x16x32_f16(ka, bQ0, sc[nt], 0, 0, 0);
            sc[nt] = __builtin_amdgcn_mfma_f32_16x16x32_f16(kb, bQ1, sc[nt], 0, 0, 0);
        }
        __builtin_amdgcn_s_setprio(0);

        // softmax for q=c: lane-local 16 keys + 2 cross-group shfls
        float tmax = sc[0][0];
#pragma unroll
        for (int nt = 0; nt < 4; ++nt)
#pragma unroll
            for (int r = 0; r < 4; ++r) tmax = fmaxf(tmax, sc[nt][r]);
        tmax = fmaxf(tmax, __shfl_xor(tmax, 16));
        tmax = fmaxf(tmax, __shfl_xor(tmax, 32));

        // defer-max (T13): rescale only when some row's max grew by >8
        if (!__all(tmax <= m_run + 8.f)) {
            const float mnew = fmaxf(m_run, tmax);
            const float fac = exp2_fast(m_run - mnew);   // 0 on first tile
            m_run = mnew;
            l_run *= fac;
#pragma unroll
            for (int r = 0; r < 4; ++r) {
                const float fr = __shfl(fac, (lane & 48) + ((lane >> 4) & 3) * 4 + r);
                oa[0][r] *= fr; oa[1][r] *= fr; oa[2][r] *= fr; oa[3][r] *= fr;
            }
        }

        float e[4][4];
        float tsum = 0.f;
#pragma unroll
        for (int nt = 0; nt < 4; ++nt)
#pragma unroll
            for (int r = 0; r < 4; ++r) {
                e[nt][r] = exp2_fast(sc[nt][r] - m_run);
                tsum += e[nt][r];
            }
        tsum += __shfl_xor(tsum, 16);
        tsum += __shfl_xor(tsum, 32);
        l_run += tsum;

        // PV: A-fragment = lane's own exp values (key order = perm6 inverse)
        const f16x8 aP0 = {(f16)e[0][0], (f16)e[0][1], (f16)e[0][2], (f16)e[0][3],
                           (f16)e[1][0], (f16)e[1][1], (f16)e[1][2], (f16)e[1][3]};
        const f16x8 aP1 = {(f16)e[2][0], (f16)e[2][1], (f16)e[2][2], (f16)e[2][3],
                           (f16)e[3][0], (f16)e[3][1], (f16)e[3][2], (f16)e[3][3]};

        __builtin_amdgcn_s_setprio(1);
#pragma unroll
        for (int nt2 = 0; nt2 < 4; ++nt2) {
            const f16x8 b0 = *(const f16x8*)&Vs[nt2 * 16 + c][g * 8];        // keys' 0..31
            const f16x8 b1 = *(const f16x8*)&Vs[nt2 * 16 + c][32 + g * 8];   // keys' 32..63
            oa[nt2] = __builtin_amdgcn_mfma_f32_16x16x32_f16(aP0, b0, oa[nt2], 0, 0, 0);
            oa[nt2] = __builtin_amdgcn_mfma_f32_16x16x32_f16(aP1, b1, oa[nt2], 0, 0, 0);
        }
        __builtin_amdgcn_s_setprio(0);
    }

    // epilogue
    const float invc = 1.f / l_run;
#pragma unroll
    for (int r = 0; r < 4; ++r) {
        const float ir = __shfl(invc, (lane & 48) + ((lane >> 4) & 3) * 4 + r);
        const int srow = qrow0 + ((lane >> 4) & 3) * 4 + r;
#pragma unroll
        for (int nt2 = 0; nt2 < 4; ++nt2) {
            ao[((size_t)b * S_LEN + srow) * D_MODEL + h * DK + nt2 * 16 + c] = (f16)(oa[nt2][r] * ir);
        }
    }
}

// ---------------------------------------------------------------------------
extern "C" void kernel_launch(void* const* d_in, const int* in_sizes, int n_in,
                              void* d_out, int out_size, void* d_ws, size_t ws_size,
                              hipStream_t stream) {
    const float* Q  = (const float*)d_in[0];
    const float* K  = (const float*)d_in[1];
    const float* V  = (const float*)d_in[2];
    const float* Wq = (const float*)d_in[3];
    const float* bq = (const float*)d_in[4];
    const float* Wk = (const float*)d_in[5];
    const float* bk = (const float*)d_in[6];
    const float* Wv = (const float*)d_in[7];
    const float* bv = (const float*)d_in[8];
    const float* Wo = (const float*)d_in[9];
    const float* bo = (const float*)d_in[10];
    float* out = (float*)d_out;

    const size_t NELEM = (size_t)M_ROWS * D_MODEL;   // 4M
    const size_t WELEM = (size_t)D_MODEL * D_MODEL;  // 1M
    f16* Qf  = (f16*)d_ws;
    f16* Kf  = Qf + NELEM;
    f16* Vf  = Kf + NELEM;
    f16* Wqf = Vf + NELEM;
    f16* Wkf = Wqf + WELEM;
    f16* Wvf = Wkf + WELEM;
    f16* Wof = Wvf + WELEM;
    f16* qh  = Wof + WELEM;   // [bh][s][dk], pre-scaled by 0.125*log2e
    f16* kh  = qh + NELEM;    // [bh][s][dk]
    f16* vtw = kh + NELEM;    // [bh][dk][s'] (perm6 key order)
    f16* aow = vtw + NELEM;   // [b][s][d_model] f16

    cvt7<<<dim3(2048, 7), 256, 0, stream>>>(Q, K, V, Wq, Wk, Wv, Wo,
                                            Qf, Kf, Vf, Wqf, Wkf, Wvf, Wof,
                                            (int)(NELEM / 8), (int)(WELEM / 8));
    qkv_gemm<<<dim3(D_MODEL / 128, M_ROWS / 128, 3), 256, 0, stream>>>(
        Qf, Kf, Vf, Wqf, Wkf, Wvf, bq, bk, bv, qh, kh, vtw);
    flash_mfma<<<dim3(S_LEN / 64, BATCH * NH), 256, 0, stream>>>(qh, kh, vtw, aow);
    out_gemm<<<dim3(D_MODEL / 128, M_ROWS / 64), 256, 0, stream>>>(aow, Wof, bo, out);
}